// Round 1
// baseline (5991.338 us; speedup 1.0000x reference)
//
#include <hip/hip_runtime.h>

typedef __attribute__((ext_vector_type(8))) short short8;
typedef __attribute__((ext_vector_type(4))) float f32x4;

#define OSTEP (256*1408)

// ---- ws layout (ushort elems from base) ----
#define OFF_WIH  ((size_t)0)
#define OFF_WHH  ((size_t)3145728)
#define OFF_WP1  ((size_t)6291456)
#define OFF_WQ1  ((size_t)7340032)
#define OFF_WP2  ((size_t)9437184)
#define OFF_WQ2  ((size_t)9568256)
#define OFF_HBF0 ((size_t)9699328)
#define OFF_HBF1 ((size_t)9961472)
#define OFF_EBF  ((size_t)10223616)
#define OFF_P1E  ((size_t)10485760)
#define OFF_Q1E  ((size_t)10747904)
#define F32_BYTE_OFF ((size_t)22020096)   // start of fp32 region (16B aligned)

__device__ __forceinline__ unsigned short f2bf(float f){
  union { float f; unsigned u; } v; v.f = f;
  unsigned u = v.u;
  u += 0x7fffu + ((u >> 16) & 1u);
  return (unsigned short)(u >> 16);
}
__device__ __forceinline__ float sigf(float x){ return 1.0f/(1.0f+__expf(-x)); }
__device__ __forceinline__ float tanhf_(float x){
  float e = __expf(-2.0f*fabsf(x));
  float t = (1.0f-e)/(1.0f+e);
  return x>=0.f ? t : -t;
}
__device__ __forceinline__ float eluf(float x){ return x>0.f ? x : __expf(x)-1.0f; }
__device__ __forceinline__ float softplusf(float x){ return x>20.f ? x : log1pf(__expf(x)); }
__device__ __forceinline__ short8 ld8(const unsigned short* p){ return *(const short8*)p; }

// ---------------- prep: fp32 -> bf16 weight conversion ----------------
__global__ void k_prep(const float* __restrict__ wih, const float* __restrict__ whh,
                       const float* __restrict__ wp1, const float* __restrict__ wq1,
                       const float* __restrict__ wp2, const float* __restrict__ wq2,
                       unsigned short* __restrict__ dst){
  size_t i4 = ((size_t)blockIdx.x*256 + threadIdx.x)*4;
  const size_t total = 9699328;
  if(i4 >= total) return;
  const float* src; size_t off;
  if(i4 < 3145728){ src=wih; off=0; }
  else if(i4 < 6291456){ src=whh; off=3145728; }
  else if(i4 < 7340032){ src=wp1; off=6291456; }
  else if(i4 < 9437184){ src=wq1; off=7340032; }
  else if(i4 < 9568256){ src=wp2; off=9437184; }
  else { src=wq2; off=9568256; }
  size_t j = i4 - off;
  float4 v = *(const float4*)(src + j);
  unsigned long long p = (unsigned long long)f2bf(v.x)
                       | ((unsigned long long)f2bf(v.y) << 16)
                       | ((unsigned long long)f2bf(v.z) << 32)
                       | ((unsigned long long)f2bf(v.w) << 48);
  *(unsigned long long*)(dst + i4) = p;
}

// ---------------- K1: GRU (gi, gh, gates, h_new) ----------------
// grid(32, 8): x = d-tile (32 cols), y = b-tile (32 rows). block = 384 (6 waves).
__global__ __launch_bounds__(384) void k_gru(
    const unsigned short* __restrict__ e_bf,
    const unsigned short* __restrict__ h_bf,
    const unsigned short* __restrict__ wih_bf,
    const unsigned short* __restrict__ whh_bf,
    const float* __restrict__ b_ih, const float* __restrict__ b_hh,
    const float* __restrict__ hprev, int hprev_ld,
    float* __restrict__ out_t,
    unsigned short* __restrict__ hnext_bf)
{
  int bx = blockIdx.x, by = blockIdx.y;
  int tid = threadIdx.x, w = tid >> 6, lane = tid & 63;
  int g = w % 3; bool isI = (w < 3);
  const unsigned short* A  = isI ? e_bf  : h_bf;
  const unsigned short* Bw = isI ? wih_bf : whh_bf;
  int brow = g*1024 + bx*32;
  int arow = by*32;
  int l15 = lane & 15, q8 = (lane >> 4)*8;

  f32x4 z4 = {0.f,0.f,0.f,0.f};
  f32x4 acc00=z4, acc01=z4, acc10=z4, acc11=z4;

  const unsigned short* pa0 = A  + (size_t)(arow + l15)*1024 + q8;
  const unsigned short* pa1 = pa0 + 16*1024;
  const unsigned short* pb0 = Bw + (size_t)(brow + l15)*1024 + q8;
  const unsigned short* pb1 = pb0 + 16*1024;

  #pragma unroll 4
  for(int kk=0; kk<1024; kk+=32){
    short8 a0 = ld8(pa0+kk), a1 = ld8(pa1+kk);
    short8 b0 = ld8(pb0+kk), b1 = ld8(pb1+kk);
    acc00 = __builtin_amdgcn_mfma_f32_16x16x32_bf16(a0,b0,acc00,0,0,0);
    acc01 = __builtin_amdgcn_mfma_f32_16x16x32_bf16(a0,b1,acc01,0,0,0);
    acc10 = __builtin_amdgcn_mfma_f32_16x16x32_bf16(a1,b0,acc10,0,0,0);
    acc11 = __builtin_amdgcn_mfma_f32_16x16x32_bf16(a1,b1,acc11,0,0,0);
  }

  __shared__ float sg[6][32][33];
  int rr = (lane>>4)*4;
  #pragma unroll
  for(int v=0; v<4; v++){
    sg[w][0 +rr+v][0 +l15] = acc00[v];
    sg[w][0 +rr+v][16+l15] = acc01[v];
    sg[w][16+rr+v][0 +l15] = acc10[v];
    sg[w][16+rr+v][16+l15] = acc11[v];
  }
  __syncthreads();

  for(int i=tid; i<1024; i+=384){
    int m = i>>5, n = i&31;
    int d = bx*32+n, b = by*32+m;
    float ir = sg[0][m][n] + b_ih[d];
    float iz = sg[1][m][n] + b_ih[1024+d];
    float ia = sg[2][m][n] + b_ih[2048+d];
    float hr = sg[3][m][n] + b_hh[d];
    float hz = sg[4][m][n] + b_hh[1024+d];
    float ha = sg[5][m][n] + b_hh[2048+d];
    float r = sigf(ir+hr), zz = sigf(iz+hz);
    float nn = tanhf_(ia + r*ha);
    float hold = hprev[(size_t)b*hprev_ld + d];
    float hnew = (1.f-zz)*nn + zz*hold;
    out_t[(size_t)b*1408 + d] = hnew;
    hnext_bf[(size_t)b*1024 + d] = f2bf(hnew);
  }
}

// ---------------- K2: p1 = elu(h@Wp1^T+b), q1 = elu([h,obs]@Wq1^T+b) ----------------
// grid(64, 8): x<32 -> p1 tile x ; x>=32 -> q1 tile x-32. block = 256 (4 waves).
__global__ __launch_bounds__(256) void k_heads1(
    const unsigned short* __restrict__ hnew_bf,
    const float* __restrict__ obs, int tcol,
    const unsigned short* __restrict__ wp1_bf,
    const unsigned short* __restrict__ wq1_bf,
    const float* __restrict__ bp1, const float* __restrict__ bq1,
    unsigned short* __restrict__ p1e, unsigned short* __restrict__ q1e)
{
  int bx = blockIdx.x, by = blockIdx.y;
  bool isQ = (bx >= 32); int nt = bx & 31;
  int tid = threadIdx.x, w = tid>>6, lane = tid&63;
  int mi = w & 1, ni = w >> 1;
  int l15 = lane & 15, q8 = (lane>>4)*8;
  int arowg = by*32 + mi*16 + l15;
  int browg = nt*32 + ni*16 + l15;

  f32x4 acc = {0.f,0.f,0.f,0.f};
  const unsigned short* pa = hnew_bf + (size_t)arowg*1024 + q8;

  if(!isQ){
    const unsigned short* pb = wp1_bf + (size_t)browg*1024 + q8;
    #pragma unroll 4
    for(int kk=0; kk<1024; kk+=32){
      acc = __builtin_amdgcn_mfma_f32_16x16x32_bf16(ld8(pa+kk), ld8(pb+kk), acc,0,0,0);
    }
  } else {
    const unsigned short* pb = wq1_bf + (size_t)browg*2048 + q8;
    #pragma unroll 4
    for(int kk=0; kk<1024; kk+=32){
      acc = __builtin_amdgcn_mfma_f32_16x16x32_bf16(ld8(pa+kk), ld8(pb+kk), acc,0,0,0);
    }
    const float* obsrow = obs + ((size_t)arowg*64 + tcol)*1024 + q8;
    #pragma unroll 4
    for(int kk=0; kk<1024; kk+=32){
      const float4* f = (const float4*)(obsrow + kk);
      float4 x0 = f[0], x1 = f[1];
      short8 a;
      a[0]=(short)f2bf(x0.x); a[1]=(short)f2bf(x0.y); a[2]=(short)f2bf(x0.z); a[3]=(short)f2bf(x0.w);
      a[4]=(short)f2bf(x1.x); a[5]=(short)f2bf(x1.y); a[6]=(short)f2bf(x1.z); a[7]=(short)f2bf(x1.w);
      acc = __builtin_amdgcn_mfma_f32_16x16x32_bf16(a, ld8(pb+1024+kk), acc,0,0,0);
    }
  }

  const float* bias = isQ ? bq1 : bp1;
  unsigned short* dst = isQ ? q1e : p1e;
  int col = browg;  // n of frag = lane&15 -> same as weight row
  float bv = bias[col];
  #pragma unroll
  for(int v=0; v<4; v++){
    int b = by*32 + mi*16 + (lane>>4)*4 + v;
    float val = eluf(acc[v] + bv);
    dst[(size_t)b*1024 + col] = f2bf(val);
  }
}

// ---------------- K3: pm = p1e@Wp2^T+bp2 ; qm = q1e@Wq2^T+bq2 ----------------
// grid(8, 8): x = 32-col tile over [pm(128) | qm(128)].
__global__ __launch_bounds__(256) void k_heads2(
    const unsigned short* __restrict__ p1e, const unsigned short* __restrict__ q1e,
    const unsigned short* __restrict__ wp2_bf, const unsigned short* __restrict__ wq2_bf,
    const float* __restrict__ bp2, const float* __restrict__ bq2,
    float* __restrict__ pm, float* __restrict__ qm)
{
  int bx = blockIdx.x, by = blockIdx.y;
  int col0 = bx*32; bool isQ = (col0 >= 128); int c0 = col0 & 127;
  int tid = threadIdx.x, w = tid>>6, lane = tid&63;
  int mi = w & 1, ni = w >> 1;
  int l15 = lane & 15, q8 = (lane>>4)*8;
  const unsigned short* A  = isQ ? q1e : p1e;
  const unsigned short* Bw = isQ ? wq2_bf : wp2_bf;
  const float* bias = isQ ? bq2 : bp2;
  float* outb = isQ ? qm : pm;

  int arowg = by*32 + mi*16 + l15;
  int browg = c0 + ni*16 + l15;
  f32x4 acc = {0.f,0.f,0.f,0.f};
  const unsigned short* pa = A  + (size_t)arowg*1024 + q8;
  const unsigned short* pb = Bw + (size_t)browg*1024 + q8;
  #pragma unroll 4
  for(int kk=0; kk<1024; kk+=32){
    acc = __builtin_amdgcn_mfma_f32_16x16x32_bf16(ld8(pa+kk), ld8(pb+kk), acc,0,0,0);
  }
  float bv = bias[browg];
  #pragma unroll
  for(int v=0; v<4; v++){
    int b = by*32 + mi*16 + (lane>>4)*4 + v;
    outb[(size_t)b*128 + browg] = acc[v] + bv;
  }
}

// ---------------- K4: sampling + output writes + e_next ----------------
// grid(32, 8): x = d-tile of e_next, y = b-tile. block 256.
__global__ __launch_bounds__(256) void k_sample_e(
    int t_out, int t_act,
    const float* __restrict__ pm, const float* __restrict__ qm,
    const float* __restrict__ noise_p, const float* __restrict__ noise_q,
    const float* __restrict__ act, const float* __restrict__ w_sa,
    const float* __restrict__ b_sa,
    float* __restrict__ out, unsigned short* __restrict__ e_bf)
{
  __shared__ float qst[32*64];
  __shared__ float sact[32*32];
  int bx = blockIdx.x, by = blockIdx.y, tid = threadIdx.x;

  if(t_out >= 0){
    float* out_t = out + (size_t)t_out*OSTEP;
    for(int i=tid; i<2048; i+=256){
      int m = i>>6, s = i&63; int b = by*32+m;
      float qmean = qm[(size_t)b*128 + s];
      float qstd  = softplusf(qm[(size_t)b*128 + 64 + s]) + 0.1f;
      float qs = qmean + qstd * noise_q[((size_t)t_out*256 + b)*64 + s];
      qst[m*64+s] = qs;
      if(bx == 0){
        float pmean = pm[(size_t)b*128 + s];
        float pstd  = softplusf(pm[(size_t)b*128 + 64 + s]) + 0.1f;
        float ps = pmean + pstd * noise_p[((size_t)t_out*256 + b)*64 + s];
        float* o = out_t + (size_t)b*1408;
        o[1024+s] = pmean; o[1088+s] = pstd; o[1152+s] = ps;
        o[1216+s] = qmean; o[1280+s] = qstd; o[1344+s] = qs;
      }
    }
  } else {
    for(int i=tid; i<2048; i+=256) qst[i] = 0.f;
  }
  for(int i=tid; i<1024; i+=256){
    int m = i>>5, k = i&31;
    sact[i] = act[((size_t)(by*32+m)*64 + t_act)*32 + k];
  }
  __syncthreads();

  int n = tid & 31, mb = tid >> 5;
  int d = bx*32 + n;
  const float* wrow = w_sa + (size_t)d*96;
  float a0=b_sa[d], a1=a0, a2=a0, a3=a0;
  for(int k=0; k<64; k++){
    float wv = wrow[k];
    a0 += qst[(mb+ 0)*64+k]*wv;
    a1 += qst[(mb+ 8)*64+k]*wv;
    a2 += qst[(mb+16)*64+k]*wv;
    a3 += qst[(mb+24)*64+k]*wv;
  }
  for(int k=0; k<32; k++){
    float wv = wrow[64+k];
    a0 += sact[(mb+ 0)*32+k]*wv;
    a1 += sact[(mb+ 8)*32+k]*wv;
    a2 += sact[(mb+16)*32+k]*wv;
    a3 += sact[(mb+24)*32+k]*wv;
  }
  e_bf[(size_t)(by*32+mb+ 0)*1024 + d] = f2bf(eluf(a0));
  e_bf[(size_t)(by*32+mb+ 8)*1024 + d] = f2bf(eluf(a1));
  e_bf[(size_t)(by*32+mb+16)*1024 + d] = f2bf(eluf(a2));
  e_bf[(size_t)(by*32+mb+24)*1024 + d] = f2bf(eluf(a3));
}

extern "C" void kernel_launch(void* const* d_in, const int* in_sizes, int n_in,
                              void* d_out, int out_size, void* d_ws, size_t ws_size,
                              hipStream_t stream) {
  const float* obs = (const float*)d_in[0];
  const float* act = (const float*)d_in[1];
  const float* np_ = (const float*)d_in[2];
  const float* nq_ = (const float*)d_in[3];
  const float* wsa = (const float*)d_in[4];
  const float* bsa = (const float*)d_in[5];
  const float* wih = (const float*)d_in[6];
  const float* bih = (const float*)d_in[7];
  const float* whh = (const float*)d_in[8];
  const float* bhh = (const float*)d_in[9];
  const float* wp1 = (const float*)d_in[10];
  const float* bp1 = (const float*)d_in[11];
  const float* wp2 = (const float*)d_in[12];
  const float* bp2 = (const float*)d_in[13];
  const float* wq1 = (const float*)d_in[14];
  const float* bq1 = (const float*)d_in[15];
  const float* wq2 = (const float*)d_in[16];
  const float* bq2 = (const float*)d_in[17];
  float* out = (float*)d_out;

  unsigned short* wsb = (unsigned short*)d_ws;
  unsigned short* wihb = wsb + OFF_WIH;
  unsigned short* whhb = wsb + OFF_WHH;
  unsigned short* wp1b = wsb + OFF_WP1;
  unsigned short* wq1b = wsb + OFF_WQ1;
  unsigned short* wp2b = wsb + OFF_WP2;
  unsigned short* wq2b = wsb + OFF_WQ2;
  unsigned short* hbf0 = wsb + OFF_HBF0;
  unsigned short* hbf1 = wsb + OFF_HBF1;
  unsigned short* ebf  = wsb + OFF_EBF;
  unsigned short* p1e  = wsb + OFF_P1E;
  unsigned short* q1e  = wsb + OFF_Q1E;
  float* f32b = (float*)((char*)d_ws + F32_BYTE_OFF);
  float* h0 = f32b;
  float* pm = f32b + 262144;
  float* qm = f32b + 262144 + 32768;

  hipMemsetAsync(hbf0, 0, 262144*2, stream);
  hipMemsetAsync(h0, 0, 262144*4, stream);

  k_prep<<<9472, 256, 0, stream>>>(wih, whh, wp1, wq1, wp2, wq2, wsb);

  // e_0 with s0 = 0
  k_sample_e<<<dim3(32,8), 256, 0, stream>>>(-1, 0, pm, qm, np_, nq_, act, wsa, bsa, out, ebf);

  for(int t=0; t<63; t++){
    const unsigned short* hb = (t&1) ? hbf1 : hbf0;
    unsigned short* hbn      = (t&1) ? hbf0 : hbf1;
    const float* hprev = t ? (out + (size_t)(t-1)*OSTEP) : h0;
    int hld = t ? 1408 : 1024;
    k_gru<<<dim3(32,8), 384, 0, stream>>>(ebf, hb, wihb, whhb, bih, bhh,
                                          hprev, hld, out + (size_t)t*OSTEP, hbn);
    k_heads1<<<dim3(64,8), 256, 0, stream>>>(hbn, obs, t+1, wp1b, wq1b, bp1, bq1, p1e, q1e);
    k_heads2<<<dim3(8,8), 256, 0, stream>>>(p1e, q1e, wp2b, wq2b, bp2, bq2, pm, qm);
    k_sample_e<<<dim3(32,8), 256, 0, stream>>>(t, t+1, pm, qm, np_, nq_, act, wsa, bsa, out, ebf);
  }
}